// Round 7
// baseline (2012.197 us; speedup 1.0000x reference)
//
#include <hip/hip_runtime.h>
#include <hip/hip_bf16.h>

typedef __hip_bfloat16 bf16;
typedef unsigned short ushort_t;
typedef short bhalf8 __attribute__((ext_vector_type(8)));
typedef float floatx4 __attribute__((ext_vector_type(4)));

#define SLEN 4096
#define DMODEL 768
#define NHEAD 12
#define DHEAD 64
#define NLAYER 4
#define FFDIM 3072
#define WIN 256
#define QB 64
#define NKT 9   // 576 window keys = 9 tiles of 64
#define VT_PLANE (NHEAD*DHEAD*SLEN)   // 12*64*4096 ushorts per half

__device__ __forceinline__ float wave_sum(float v){
  #pragma unroll
  for (int off = 32; off; off >>= 1) v += __shfl_xor(v, off, 64);
  return v;
}

__device__ __forceinline__ ushort_t f2bf(float x){
  unsigned u = __float_as_uint(x);
  unsigned r = u + 0x7FFFu + ((u >> 16) & 1u);   // RTNE
  return (ushort_t)(r >> 16);
}
__device__ __forceinline__ float bf2f(ushort_t h){
  return __uint_as_float((unsigned)h << 16);
}

__device__ __forceinline__ floatx4 mfma_bf16(bhalf8 a, bhalf8 b, floatx4 c){
  asm("v_mfma_f32_16x16x32_bf16 %0, %1, %2, %0" : "+v"(c) : "v"(a), "v"(b));
  return c;
}

__device__ __forceinline__ void split8(const float* xs, bhalf8& hi, bhalf8& lo){
  union { ushort_t u[8]; bhalf8 v; } H, L;
  #pragma unroll
  for (int j = 0; j < 8; j++){
    ushort_t h = f2bf(xs[j]);
    H.u[j] = h;
    L.u[j] = f2bf(xs[j] - bf2f(h));
  }
  hi = H.v; lo = L.v;
}

// ---------------- embedding + LayerNorm: one wave per row ----------------
__global__ __launch_bounds__(256) void embed_ln_kernel(
    const int* __restrict__ ids, const float* __restrict__ we,
    const float* __restrict__ pe, const float* __restrict__ g,
    const float* __restrict__ b, float* __restrict__ x){
  int row  = blockIdx.x*4 + (threadIdx.x >> 6);
  int lane = threadIdx.x & 63;
  int id = ids[row];
  float e[12];
  float sum = 0.f;
  #pragma unroll
  for (int i = 0; i < 12; i++){
    int c = lane + i*64;
    e[i] = we[(size_t)id*DMODEL + c] + pe[(size_t)row*DMODEL + c];
    sum += e[i];
  }
  float mean = wave_sum(sum) * (1.f/DMODEL);
  float vs = 0.f;
  #pragma unroll
  for (int i = 0; i < 12; i++){ float d = e[i] - mean; vs += d*d; }
  float inv = 1.f / sqrtf(wave_sum(vs)*(1.f/DMODEL) + 1e-5f);
  #pragma unroll
  for (int i = 0; i < 12; i++){
    int c = lane + i*64;
    x[(size_t)row*DMODEL + c] = (e[i] - mean)*inv*g[c] + b[c];
  }
}

// ---------------- LayerNorm: one wave per row ----------------
__global__ __launch_bounds__(256) void ln_kernel(
    const float* __restrict__ in, float* __restrict__ out,
    const float* __restrict__ g, const float* __restrict__ b){
  int row  = blockIdx.x*4 + (threadIdx.x >> 6);
  int lane = threadIdx.x & 63;
  float e[12];
  float sum = 0.f;
  #pragma unroll
  for (int i = 0; i < 12; i++){
    e[i] = in[(size_t)row*DMODEL + lane + i*64];
    sum += e[i];
  }
  float mean = wave_sum(sum) * (1.f/DMODEL);
  float vs = 0.f;
  #pragma unroll
  for (int i = 0; i < 12; i++){ float d = e[i] - mean; vs += d*d; }
  float inv = 1.f / sqrtf(wave_sum(vs)*(1.f/DMODEL) + 1e-5f);
  #pragma unroll
  for (int i = 0; i < 12; i++){
    int c = lane + i*64;
    out[(size_t)row*DMODEL + c] = (e[i] - mean)*inv*g[c] + b[c];
  }
}

// ---------------- split+transpose weight W[K][Nw] fp32 -> T[2][K/8][Ntot][8] bf16 ----------------
__global__ __launch_bounds__(256) void split_b_kernel(
    const float* __restrict__ W, ushort_t* __restrict__ T,
    int Nw, int Ntot, int K, int noff){
  int n  = blockIdx.x*256 + threadIdx.x;
  int kc = blockIdx.y;
  float xs[8];
  #pragma unroll
  for (int j = 0; j < 8; j++) xs[j] = W[(size_t)(kc*8 + j)*Nw + n];
  union { ushort_t u[8]; uint4 v; } ph, pl;
  #pragma unroll
  for (int j = 0; j < 8; j++){
    ushort_t h = f2bf(xs[j]);
    ph.u[j] = h;
    pl.u[j] = f2bf(xs[j] - bf2f(h));
  }
  size_t KC = (size_t)(K >> 3);
  *reinterpret_cast<uint4*>(T + ((size_t)kc*Ntot + noff + n)*8)        = ph.v;
  *reinterpret_cast<uint4*>(T + ((KC + kc)*Ntot + noff + n)*8)         = pl.v;
}

// ---------------- split-bf16 MFMA GEMM, BM=64 BN=NTILE, dbuf prefetch, XCD swizzle ----------------
// A: fp32 activations [M][K], split hi/lo in-kernel during staging.
// B: pre-split bf16 [2][K/8][N][8].
// mode 0: C = (A@B+bias)*scale [+resid]   mode 1: C = gelu(A@B+bias)
// mode 2: fused QKV (N=2304): q / k_out / vt_out by column section (64|768).
template<int NTILE>
__global__ __launch_bounds__(256) void gemm_mfma_kernel(
    const float* __restrict__ Afp, const ushort_t* __restrict__ pBt,
    const float* __restrict__ bias, const float* __restrict__ bias2,
    const float* __restrict__ bias3, const float* __restrict__ resid,
    float* __restrict__ Cm, float* __restrict__ k_out,
    ushort_t* __restrict__ vt_out,
    int M, int N, int K, float scale, int mode){
  constexpr int NI = NTILE/32;          // col fragments per wave
  constexpr int NCH = NTILE/64;         // 64-row chunks per (half,kg) of B
  __shared__ __align__(16) ushort_t LA[2][2][4][64][8];
  __shared__ __align__(16) ushort_t LB[2][2][4][NTILE][8];
  const int tid  = threadIdx.x;
  const int w    = tid >> 6;
  const int lane = tid & 63;
  const int wr = w >> 1, wc = w & 1;

  // bijective XCD swizzle: same-A-panel tiles land on the same XCD L2
  int bx = blockIdx.x, by = blockIdx.y;
  {
    int nwg = gridDim.x*gridDim.y;
    if ((nwg & 7) == 0){
      int lin = by*gridDim.x + bx;
      int lin2 = (lin & 7)*(nwg >> 3) + (lin >> 3);
      bx = lin2 % gridDim.x;
      by = lin2 / gridDim.x;
    }
  }
  const int r0 = by*64, c0 = bx*NTILE;
  const int fr = lane & 15, fq = lane >> 4;
  const size_t KC = (size_t)(K >> 3);
  const size_t planeB = (size_t)N*8;

  // A staging: thread t -> (row = t>>2, kg = t&3), 32B contiguous per thread
  const int arow = tid >> 2;
  const int akg  = tid & 3;
  const float* asrc = Afp + (size_t)(r0 + arow)*K + akg*8;

  floatx4 acc[2][NI] = {};
  const int nstep = K >> 5;

  // ---- prologue: stage step 0 into buf 0 ----
  #pragma unroll
  for (int c = 0; c < 2*NCH; c++){
    int idx = w*(2*NCH) + c;
    int chunk = idx % NCH, rem = idx / NCH;
    int kg = rem & 3, half = rem >> 2;
    const ushort_t* sp = pBt + (size_t)half*KC*planeB + (size_t)kg*planeB
                       + (size_t)(c0 + chunk*64 + lane)*8;
    ushort_t* dp = &LB[0][half][kg][chunk*64][0];
    __builtin_amdgcn_global_load_lds(
        (const __attribute__((address_space(1))) void*)sp,
        (__attribute__((address_space(3))) void*)dp, 16, 0, 0);
  }
  {
    float4 a0 = *reinterpret_cast<const float4*>(asrc);
    float4 a1 = *reinterpret_cast<const float4*>(asrc + 4);
    asm volatile("s_waitcnt vmcnt(0)" ::: "memory");
    float xs[8] = {a0.x,a0.y,a0.z,a0.w,a1.x,a1.y,a1.z,a1.w};
    bhalf8 hi, lo; split8(xs, hi, lo);
    *reinterpret_cast<bhalf8*>(&LA[0][0][akg][arow][0]) = hi;
    *reinterpret_cast<bhalf8*>(&LA[0][1][akg][arow][0]) = lo;
  }
  __syncthreads();

  int cur = 0;
  for (int s = 0; s < nstep; ++s){
    const bool pf = (s+1 < nstep);
    float4 pa0, pa1;
    if (pf){
      const int kcb = (s+1) << 2;
      #pragma unroll
      for (int c = 0; c < 2*NCH; c++){
        int idx = w*(2*NCH) + c;
        int chunk = idx % NCH, rem = idx / NCH;
        int kg = rem & 3, half = rem >> 2;
        const ushort_t* sp = pBt + (size_t)half*KC*planeB + (size_t)(kcb + kg)*planeB
                           + (size_t)(c0 + chunk*64 + lane)*8;
        ushort_t* dp = &LB[cur^1][half][kg][chunk*64][0];
        __builtin_amdgcn_global_load_lds(
            (const __attribute__((address_space(1))) void*)sp,
            (__attribute__((address_space(3))) void*)dp, 16, 0, 0);
      }
      const float* p = asrc + (size_t)(s+1)*32;
      pa0 = *reinterpret_cast<const float4*>(p);
      pa1 = *reinterpret_cast<const float4*>(p + 4);
    }

    // ---- compute current tile ----
    bhalf8 ah[2], al[2], bh[NI], bl[NI];
    #pragma unroll
    for (int mi = 0; mi < 2; mi++){
      int row = wr*32 + mi*16 + fr;
      ah[mi] = *reinterpret_cast<const bhalf8*>(&LA[cur][0][fq][row][0]);
      al[mi] = *reinterpret_cast<const bhalf8*>(&LA[cur][1][fq][row][0]);
    }
    #pragma unroll
    for (int ni = 0; ni < NI; ni++){
      int col = wc*(NTILE/2) + ni*16 + fr;
      bh[ni] = *reinterpret_cast<const bhalf8*>(&LB[cur][0][fq][col][0]);
      bl[ni] = *reinterpret_cast<const bhalf8*>(&LB[cur][1][fq][col][0]);
    }
    #pragma unroll
    for (int mi = 0; mi < 2; mi++)
      #pragma unroll
      for (int ni = 0; ni < NI; ni++)
        acc[mi][ni] = mfma_bf16(ah[mi], bh[ni], acc[mi][ni]);
    #pragma unroll
    for (int mi = 0; mi < 2; mi++)
      #pragma unroll
      for (int ni = 0; ni < NI; ni++)
        acc[mi][ni] = mfma_bf16(ah[mi], bl[ni], acc[mi][ni]);
    #pragma unroll
    for (int mi = 0; mi < 2; mi++)
      #pragma unroll
      for (int ni = 0; ni < NI; ni++)
        acc[mi][ni] = mfma_bf16(al[mi], bh[ni], acc[mi][ni]);

    if (pf){
      asm volatile("s_waitcnt vmcnt(0)" ::: "memory");   // A regs + B LDS landed
      float xs[8] = {pa0.x,pa0.y,pa0.z,pa0.w,pa1.x,pa1.y,pa1.z,pa1.w};
      bhalf8 hi, lo; split8(xs, hi, lo);
      *reinterpret_cast<bhalf8*>(&LA[cur^1][0][akg][arow][0]) = hi;
      *reinterpret_cast<bhalf8*>(&LA[cur^1][1][akg][arow][0]) = lo;
    }
    __syncthreads();
    cur ^= 1;
  }

  // ---- epilogue ----
  if (mode == 2){
    const int sect = c0 / DMODEL;           // 0=q, 1=k, 2=v (64-col tiles never straddle)
    const int coff = c0 - sect*DMODEL;
    #pragma unroll
    for (int mi = 0; mi < 2; mi++){
      #pragma unroll
      for (int ni = 0; ni < NI; ni++){
        int col = coff + wc*(NTILE/2) + ni*16 + fr;
        int row0 = r0 + wr*32 + mi*16 + fq*4;
        if (sect == 0){
          float bb = bias[col];
          #pragma unroll
          for (int j = 0; j < 4; j++)
            Cm[(size_t)(row0+j)*DMODEL + col] = (acc[mi][ni][j] + bb) * scale;
        } else if (sect == 1){
          float bb = bias2[col];
          #pragma unroll
          for (int j = 0; j < 4; j++)
            k_out[(size_t)(row0+j)*DMODEL + col] = acc[mi][ni][j] + bb;
        } else {
          float bb = bias3[col];
          unsigned long long phi = 0ull, plo = 0ull;
          #pragma unroll
          for (int j = 0; j < 4; j++){
            float vo = acc[mi][ni][j] + bb;
            ushort_t hh = f2bf(vo);
            ushort_t ll = f2bf(vo - bf2f(hh));
            phi |= (unsigned long long)hh << (16*j);
            plo |= (unsigned long long)ll << (16*j);
          }
          size_t base = (size_t)col*SLEN + row0;
          *reinterpret_cast<unsigned long long*>(&vt_out[base])            = phi;
          *reinterpret_cast<unsigned long long*>(&vt_out[VT_PLANE + base]) = plo;
        }
      }
    }
    return;
  }

  #pragma unroll
  for (int mi = 0; mi < 2; mi++){
    #pragma unroll
    for (int ni = 0; ni < NI; ni++){
      int col = c0 + wc*(NTILE/2) + ni*16 + fr;
      float bb = bias[col];
      #pragma unroll
      for (int j = 0; j < 4; j++){
        int row = r0 + wr*32 + mi*16 + fq*4 + j;
        float vo = (acc[mi][ni][j] + bb) * scale;
        if (mode == 1) vo = 0.5f*vo*(1.f + erff(vo*0.70710678118654752f));
        if (resid) vo += resid[(size_t)row*N + col];
        Cm[(size_t)row*N + col] = vo;
      }
    }
  }
}

// ---------------- banded attention: flash-style MFMA, split-bf16 (validated r4) ----------------
__global__ __launch_bounds__(128) void band_attn_kernel(
    const float* __restrict__ q, const float* __restrict__ k,
    const ushort_t* __restrict__ vt, const int* __restrict__ mask,
    float* __restrict__ ao){
  __shared__ __align__(16) ushort_t KHs[8][65][8];
  __shared__ __align__(16) ushort_t KLs[8][65][8];
  __shared__ __align__(16) ushort_t VHs[8][65][8];
  __shared__ __align__(16) ushort_t VLs[8][65][8];
  __shared__ __align__(16) ushort_t PHs[2][8][33][8];
  __shared__ __align__(16) ushort_t PLs[2][8][33][8];
  __shared__ float aL[2][32];
  __shared__ float lL[2][32];

  const int h    = blockIdx.y;
  const int q0   = blockIdx.x * QB;
  const int tid  = threadIdx.x;
  const int w    = tid >> 6;
  const int lane = tid & 63;
  const int fr   = lane & 15;
  const int fq   = lane >> 4;
  const int kstart = q0 - WIN;

  bhalf8 QHr[2][2], QLr[2][2];
  #pragma unroll
  for (int cf = 0; cf < 2; cf++)
    #pragma unroll
    for (int s = 0; s < 2; s++){
      const float* qp = q + (size_t)(q0 + 32*w + 16*cf + fr)*DMODEL
                      + h*DHEAD + s*32 + fq*8;
      float4 a = *reinterpret_cast<const float4*>(qp);
      float4 b = *reinterpret_cast<const float4*>(qp + 4);
      float xs[8] = {a.x,a.y,a.z,a.w,b.x,b.y,b.z,b.w};
      split8(xs, QHr[cf][s], QLr[cf][s]);
    }

  floatx4 acc_o[2][4] = {};
  float mreg[2] = {0.f, 0.f};
  float lreg[2] = {0.f, 0.f};

  const int rK = 32*w + (lane >> 1);
  const int hd = lane & 1;

  for (int t = 0; t < NKT; t++){
    const int g0 = kstart + t*64;

    {
      int g = min(max(g0 + rK, 0), SLEN-1);
      const float* kp = k + (size_t)g*DMODEL + h*DHEAD + hd*32;
      #pragma unroll
      for (int i = 0; i < 4; i++){
        float4 a = *reinterpret_cast<const float4*>(kp + i*8);
        float4 b = *reinterpret_cast<const float4*>(kp + i*8 + 4);
        float xs[8] = {a.x,a.y,a.z,a.w,b.x,b.y,b.z,b.w};
        bhalf8 hi, lo; split8(xs, hi, lo);
        int kg = hd*4 + i;
        *reinterpret_cast<bhalf8*>(&KHs[kg][rK][0]) = hi;
        *reinterpret_cast<bhalf8*>(&KLs[kg][rK][0]) = lo;
      }
      const ushort_t* vrow = vt + (size_t)(h*DHEAD + rK)*SLEN;
      #pragma unroll
      for (int i = 0; i < 4; i++){
        int kk = min(max(g0 + hd*32 + i*8, 0), SLEN-8);
        uint4 hv = *reinterpret_cast<const uint4*>(&vrow[kk]);
        uint4 lv = *reinterpret_cast<const uint4*>(&vrow[VT_PLANE + kk]);
        int u = hd*4 + i;
        *reinterpret_cast<uint4*>(&VHs[u][rK][0]) = hv;
        *reinterpret_cast<uint4*>(&VLs[u][rK][0]) = lv;
      }
    }
    __syncthreads();

    int gmk = g0 + lane;
    bool kvv = ((unsigned)gmk < (unsigned)SLEN) &&
               (mask[min(max(gmk,0),SLEN-1)] != 0);
    unsigned long long bal = __ballot(kvv);

    floatx4 acc_s[4][2] = {};
    #pragma unroll
    for (int s = 0; s < 2; s++)
      #pragma unroll
      for (int kf = 0; kf < 4; kf++){
        int row = 16*kf + fr;
        int kg  = s*4 + fq;
        bhalf8 KHf = *reinterpret_cast<const bhalf8*>(&KHs[kg][row][0]);
        bhalf8 KLf = *reinterpret_cast<const bhalf8*>(&KLs[kg][row][0]);
        #pragma unroll
        for (int cf = 0; cf < 2; cf++){
          acc_s[kf][cf] = mfma_bf16(KHf, QHr[cf][s], acc_s[kf][cf]);
          acc_s[kf][cf] = mfma_bf16(KHf, QLr[cf][s], acc_s[kf][cf]);
          acc_s[kf][cf] = mfma_bf16(KLf, QHr[cf][s], acc_s[kf][cf]);
        }
      }

    #pragma unroll
    for (int cf = 0; cf < 2; cf++){
      int qloc = 32*w + 16*cf + fr;
      float mx = -1e30f;
      #pragma unroll
      for (int kf = 0; kf < 4; kf++)
        #pragma unroll
        for (int j = 0; j < 4; j++){
          int key = 16*kf + fq*4 + j;
          int dj  = t*64 + key - WIN - qloc;
          bool ok = ((unsigned)(dj + WIN) <= 2u*WIN) && ((bal >> key) & 1ull);
          float sv = ok ? acc_s[kf][cf][j] : -1e30f;
          acc_s[kf][cf][j] = sv;
          mx = fmaxf(mx, sv);
        }
      mx = fmaxf(mx, __shfl_xor(mx, 16, 64));
      mx = fmaxf(mx, __shfl_xor(mx, 32, 64));
      float mnew  = fmaxf(mreg[cf], mx);
      float alpha = __expf(mreg[cf] - mnew);
      mreg[cf] = mnew;
      float psum = 0.f;
      #pragma unroll
      for (int kf = 0; kf < 4; kf++){
        unsigned long long phi = 0ull, plo = 0ull;
        #pragma unroll
        for (int j = 0; j < 4; j++){
          float p = __expf(acc_s[kf][cf][j] - mnew);
          psum += p;
          ushort_t hh = f2bf(p);
          ushort_t ll = f2bf(p - bf2f(hh));
          phi |= (unsigned long long)hh << (16*j);
          plo |= (unsigned long long)ll << (16*j);
        }
        int kgrp = 2*kf + (fq >> 1);
        int qrow = 16*cf + fr;
        *reinterpret_cast<unsigned long long*>(&PHs[w][kgrp][qrow][(fq&1)*4]) = phi;
        *reinterpret_cast<unsigned long long*>(&PLs[w][kgrp][qrow][(fq&1)*4]) = plo;
      }
      psum += __shfl_xor(psum, 16, 64);
      psum += __shfl_xor(psum, 32, 64);
      lreg[cf] = lreg[cf]*alpha + psum;
      if (fq == 0) aL[w][16*cf + fr] = alpha;
    }
    __syncthreads();

    #pragma unroll
    for (int mf = 0; mf < 2; mf++)
      #pragma unroll
      for (int j = 0; j < 4; j++){
        float al = aL[w][16*mf + fq*4 + j];
        #pragma unroll
        for (int ni = 0; ni < 4; ni++)
          acc_o[mf][ni][j] *= al;
      }

    #pragma unroll
    for (int ks = 0; ks < 2; ks++){
      int u = ks*4 + fq;
      bhalf8 PHf[2], PLf[2];
      #pragma unroll
      for (int mf = 0; mf < 2; mf++){
        PHf[mf] = *reinterpret_cast<const bhalf8*>(&PHs[w][u][16*mf + fr][0]);
        PLf[mf] = *reinterpret_cast<const bhalf8*>(&PLs[w][u][16*mf + fr][0]);
      }
      #pragma unroll
      for (int ni = 0; ni < 4; ni++){
        int d = 16*ni + fr;
        bhalf8 VHf = *reinterpret_cast<const bhalf8*>(&VHs[u][d][0]);
        bhalf8 VLf = *reinterpret_cast<const bhalf8*>(&VLs[u][d][0]);
        #pragma unroll
        for (int mf = 0; mf < 2; mf++){
          acc_o[mf][ni] = mfma_bf16(PHf[mf], VHf, acc_o[mf][ni]);
          acc_o[mf][ni] = mfma_bf16(PHf[mf], VLf, acc_o[mf][ni]);
          acc_o[mf][ni] = mfma_bf16(PLf[mf], VHf, acc_o[mf][ni]);
        }
      }
    }
    __syncthreads();
  }

  if (fq == 0){
    lL[w][fr]      = 1.f / lreg[0];
    lL[w][16 + fr] = 1.f / lreg[1];
  }
  __syncthreads();
  #pragma unroll
  for (int mf = 0; mf < 2; mf++)
    #pragma unroll
    for (int j = 0; j < 4; j++){
      float inv = lL[w][16*mf + fq*4 + j];
      int qg = q0 + 32*w + 16*mf + fq*4 + j;
      float* orow = ao + (size_t)qg*DMODEL + h*DHEAD;
      #pragma unroll
      for (int ni = 0; ni < 4; ni++)
        orow[16*ni + fr] = acc_o[mf][ni][j] * inv;
    }
}

// ---------------- masked mean-pool, two-stage deterministic ----------------
__global__ __launch_bounds__(256) void pool1_kernel(
    const float* __restrict__ x, const int* __restrict__ mask,
    float* __restrict__ partial){
  int b = blockIdx.x;
  int t = threadIdx.x;
  float a0 = 0.f, a1 = 0.f, a2 = 0.f;
  for (int r = b*16; r < b*16 + 16; r++){
    float mm = (float)mask[r];
    const float* row = x + (size_t)r*DMODEL;
    a0 = fmaf(row[t      ], mm, a0);
    a1 = fmaf(row[t + 256], mm, a1);
    a2 = fmaf(row[t + 512], mm, a2);
  }
  partial[(size_t)b*DMODEL + t      ] = a0;
  partial[(size_t)b*DMODEL + t + 256] = a1;
  partial[(size_t)b*DMODEL + t + 512] = a2;
}

// pool2 also computes mask sum into ps[1000]
__global__ __launch_bounds__(256) void pool2_kernel(
    const float* __restrict__ partial, const int* __restrict__ mask,
    float* __restrict__ ps){
  __shared__ float red[4];
  int c = blockIdx.x*256 + threadIdx.x;
  float a = 0.f;
  for (int p = 0; p < 256; p++) a += partial[(size_t)p*DMODEL + c];
  ps[c] = a;
  if (blockIdx.x == 0){
    int tid = threadIdx.x;
    float ms = 0.f;
    for (int r = tid; r < SLEN; r += 256) ms += (float)mask[r];
    ms = wave_sum(ms);
    if ((tid & 63) == 0) red[tid >> 6] = ms;
    __syncthreads();
    if (tid == 0) ps[1000] = red[0] + red[1] + red[2] + red[3];
  }
}

// ---------------- diagnostic probe: sumabs of first n elements ----------------
__global__ __launch_bounds__(64) void probe_kernel(
    const float* __restrict__ p, int n, float* __restrict__ slot){
  int lane = threadIdx.x;
  float s = 0.f;
  for (int i = lane; i < n; i += 64) s += fabsf(p[i]);
  s = wave_sum(s);
  if (lane == 0) slot[0] = s;
}

// ---------------- MLP head, parallelized partial-sum stages ----------------
// h1 partials: 48 blocks x 16 rows of W1[768][512]
__global__ __launch_bounds__(256) void head1a_kernel(
    const float* __restrict__ ps, const float* __restrict__ W1,
    float* __restrict__ partial1){
  int b = blockIdx.x;
  int tid = threadIdx.x;
  float inv = 1.f / fmaxf(ps[1000], 1e-9f);
  float a0 = 0.f, a1 = 0.f;
  for (int r = b*16; r < b*16 + 16; r++){
    float pr = ps[r]*inv;
    a0 = fmaf(pr, W1[(size_t)r*512 + tid      ], a0);
    a1 = fmaf(pr, W1[(size_t)r*512 + tid + 256], a1);
  }
  partial1[(size_t)b*512 + tid      ] = a0;
  partial1[(size_t)b*512 + tid + 256] = a1;
}

__global__ __launch_bounds__(256) void head1b_kernel(
    const float* __restrict__ partial1, const float* __restrict__ b1,
    float* __restrict__ h1g){
  int tid = threadIdx.x;
  #pragma unroll
  for (int jj = 0; jj < 2; jj++){
    int j = tid + jj*256;
    float a = 0.f;
    for (int p = 0; p < 48; p++) a += partial1[(size_t)p*512 + j];
    h1g[j] = fmaxf(a + b1[j], 0.f);
  }
}

// h2 partials: 16 blocks x 32 rows of W2[512][250]
__global__ __launch_bounds__(256) void head2a_kernel(
    const float* __restrict__ h1g, const float* __restrict__ W2,
    float* __restrict__ partial2){
  int b = blockIdx.x;
  int tid = threadIdx.x;
  if (tid < 250){
    float a = 0.f;
    for (int r = b*32; r < b*32 + 32; r++)
      a = fmaf(h1g[r], W2[(size_t)r*250 + tid], a);
    partial2[(size_t)b*250 + tid] = a;
  }
}

__global__ __launch_bounds__(256) void head2b_kernel(
    const float* __restrict__ partial2, const float* __restrict__ b2,
    const float* __restrict__ W3, const float* __restrict__ b3,
    const float* __restrict__ diag, bf16* __restrict__ out){
  __shared__ float h2[256];
  int tid = threadIdx.x;
  if (tid < 250){
    float a = 0.f;
    for (int p = 0; p < 16; p++) a += partial2[(size_t)p*250 + tid];
    h2[tid] = fmaxf(a + b2[tid], 0.f);
  }
  __syncthreads();
  if (tid == 0){
    float acc = b3[0];
    for (int c = 0; c < 250; c++) acc = fmaf(h2[c], W3[c], acc);
    float delta = 0.f;
    #pragma unroll
    for (int kk = 0; kk < 6; kk++){
      float dv = diag[kk];
      if (!(dv > 1e-3f)){
        delta = (dv != dv ? 8192.0f : 0.0f) + 64.0f*(kk+1);
        break;
      }
    }
    float r = acc + delta;
    union { bf16 h; unsigned short u; } cv;
    cv.h = (bf16)r;
    unsigned int packed = ((unsigned int)cv.u << 16) | (unsigned int)cv.u;
    volatile unsigned int* o32 = (volatile unsigned int*)out;
    o32[0] = packed;
    o32[1] = packed;
  }
}

extern "C" void kernel_launch(void* const* d_in, const int* in_sizes, int n_in,
                              void* d_out, int out_size, void* d_ws, size_t ws_size,
                              hipStream_t stream) {
  const int*   ids  = (const int*)d_in[0];
  const int*   mask = (const int*)d_in[1];
  const float* we   = (const float*)d_in[2];
  const float* pe   = (const float*)d_in[3];
  const float* eg   = (const float*)d_in[4];
  const float* eb   = (const float*)d_in[5];
  const float* Wq   = (const float*)d_in[6];
  const float* Wk   = (const float*)d_in[7];
  const float* Wv   = (const float*)d_in[8];
  const float* Wo   = (const float*)d_in[9];
  const float* bq   = (const float*)d_in[10];
  const float* bk   = (const float*)d_in[11];
  const float* bv   = (const float*)d_in[12];
  const float* bo   = (const float*)d_in[13];
  const float* g1   = (const float*)d_in[14];
  const float* be1  = (const float*)d_in[15];
  const float* Wf1  = (const float*)d_in[16];
  const float* bf1  = (const float*)d_in[17];
  const float* Wf2  = (const float*)d_in[18];
  const float* bf2  = (const float*)d_in[19];
  const float* g2   = (const float*)d_in[20];
  const float* be2  = (const float*)d_in[21];
  const float* W1   = (const float*)d_in[22];
  const float* b1   = (const float*)d_in[23];
  const float* W2   = (const float*)d_in[24];
  const float* b2   = (const float*)d_in[25];
  const float* W3   = (const float*)d_in[26];
  const float* b3   = (const float*)d_in[27];

  const size_t SD = (size_t)SLEN*DMODEL;
  float* x  = (float*)d_ws;
  float* y  = x  + SD;
  float* q  = y  + SD;
  float* k  = q  + SD;
  float* v  = k  + SD;            // reused as vt (split-bf16 V^T), exactly SD*4 bytes
  float* ao = v  + SD;
  float* hf = q;                  // FF phase alias (4*SD == SLEN*FFDIM)
  ushort_t* vt = (ushort_t*)v;
  float* ps       = ao + SD;           // 1024 (ps[1000] = mask sum)
  float* partial  = ps + 1024;         // 256*768
  float* diag     = partial + 256*DMODEL;  // 64
  float* partial1 = diag + 64;         // 48*512
  float* h1g      = partial1 + 48*512; // 512
  float* partial2 = h1g + 512;         // 16*250 -> pad 4096
  ushort_t* Bt = (ushort_t*)(partial2 + 4096);

  embed_ln_kernel<<<SLEN/4, 256, 0, stream>>>(ids, we, pe, eg, eb, x);
  probe_kernel<<<1, 64, 0, stream>>>(x, 512, diag + 0);

  const float qscale = 0.125f;
  dim3 gQKV((DMODEL*3)/64, SLEN/64);   // (36, 64) = 2304
  dim3 gD64(DMODEL/64,     SLEN/64);   // (12, 64) = 768
  dim3 gF1 (FFDIM/64,      SLEN/64);   // (48, 64) = 3072

  for (int l = 0; l < NLAYER; l++){
    const float* wq  = Wq  + (size_t)l*DMODEL*DMODEL;
    const float* wk  = Wk  + (size_t)l*DMODEL*DMODEL;
    const float* wv  = Wv  + (size_t)l*DMODEL*DMODEL;
    const float* wo  = Wo  + (size_t)l*DMODEL*DMODEL;
    const float* wf1 = Wf1 + (size_t)l*DMODEL*FFDIM;
    const float* wf2 = Wf2 + (size_t)l*FFDIM*DMODEL;

    // ---- fused QKV: one N=2304 GEMM ----
    split_b_kernel<<<dim3(3,96), 256, 0, stream>>>(wq, Bt, DMODEL, 3*DMODEL, DMODEL, 0);
    split_b_kernel<<<dim3(3,96), 256, 0, stream>>>(wk, Bt, DMODEL, 3*DMODEL, DMODEL, DMODEL);
    split_b_kernel<<<dim3(3,96), 256, 0, stream>>>(wv, Bt, DMODEL, 3*DMODEL, DMODEL, 2*DMODEL);
    gemm_mfma_kernel<64><<<gQKV, 256, 0, stream>>>(
        x, Bt, bq + l*DMODEL, bk + l*DMODEL, bv + l*DMODEL, nullptr,
        q, k, vt, SLEN, 3*DMODEL, DMODEL, qscale, 2);
    if (l == 0) probe_kernel<<<1, 64, 0, stream>>>(q, 512, diag + 1);
    if (l == 0) probe_kernel<<<1, 64, 0, stream>>>((const float*)vt, 512, diag + 2);

    band_attn_kernel<<<dim3(SLEN/QB, NHEAD), 128, 0, stream>>>(q, k, vt, mask, ao);
    if (l == 0) probe_kernel<<<1, 64, 0, stream>>>(ao, 512, diag + 3);

    // ---- O-proj (+resid x) ----
    split_b_kernel<<<dim3(3,96), 256, 0, stream>>>(wo, Bt, DMODEL, DMODEL, DMODEL, 0);
    gemm_mfma_kernel<64><<<gD64, 256, 0, stream>>>(
        ao, Bt, bo + l*DMODEL, nullptr, nullptr, x,
        y, nullptr, nullptr, SLEN, DMODEL, DMODEL, 1.f, 0);
    ln_kernel<<<SLEN/4, 256, 0, stream>>>(y, x, g1 + l*DMODEL, be1 + l*DMODEL);

    // ---- FF1 (gelu) ----
    split_b_kernel<<<dim3(12,96), 256, 0, stream>>>(wf1, Bt, FFDIM, FFDIM, DMODEL, 0);
    gemm_mfma_kernel<64><<<gF1, 256, 0, stream>>>(
        x, Bt, bf1 + l*FFDIM, nullptr, nullptr, nullptr,
        hf, nullptr, nullptr, SLEN, FFDIM, DMODEL, 1.f, 1);

    // ---- FF2 (+resid x) ----
    split_b_kernel<<<dim3(3,384), 256, 0, stream>>>(wf2, Bt, DMODEL, DMODEL, FFDIM, 0);
    gemm_mfma_kernel<64><<<gD64, 256, 0, stream>>>(
        hf, Bt, bf2 + l*DMODEL, nullptr, nullptr, x,
        y, nullptr, nullptr, SLEN, DMODEL, FFDIM, 1.f, 0);
    ln_kernel<<<SLEN/4, 256, 0, stream>>>(y, x, g2 + l*DMODEL, be2 + l*DMODEL);
  }
  probe_kernel<<<1, 64, 0, stream>>>(x, 512, diag + 4);

  pool1_kernel<<<256, 256, 0, stream>>>(x, mask, partial);
  pool2_kernel<<<DMODEL/256, 256, 0, stream>>>(partial, mask, ps);
  probe_kernel<<<1, 64, 0, stream>>>(ps, DMODEL, diag + 5);
  head1a_kernel<<<48, 256, 0, stream>>>(ps, W1, partial1);
  head1b_kernel<<<1, 256, 0, stream>>>(partial1, b1, h1g);
  head2a_kernel<<<16, 256, 0, stream>>>(h1g, W2, partial2);
  head2b_kernel<<<1, 256, 0, stream>>>(partial2, b2, W3, b3, diag, (bf16*)d_out);
}